// Round 5
// baseline (180.345 us; speedup 1.0000x reference)
//
#include <hip/hip_runtime.h>
#include <math.h>

constexpr int D  = 1024;
constexpr int H  = 16;
constexpr int HD = 64;
constexpr int B  = 2;
constexpr int T  = 2048;
constexpr int M  = B * T;   // 4096

constexpr size_t XSZ = (size_t)M * D;   // 4,194,304
constexpr size_t WSZ = (size_t)D * D;   // 1,048,576

typedef float  f32x4  __attribute__((ext_vector_type(4)));
typedef __bf16 bf16x8 __attribute__((ext_vector_type(8)));
typedef __bf16 bf16x4 __attribute__((ext_vector_type(4)));

static __device__ inline f32x4 mfma16(bf16x8 a, bf16x8 b, f32x4 c) {
  return __builtin_amdgcn_mfma_f32_16x16x32_bf16(a, b, c, 0, 0, 0);
}

// async global->LDS, 16B per lane (dest = wave-uniform base + lane*16)
static __device__ inline void gload16(const __bf16* g, __bf16* l) {
  __builtin_amdgcn_global_load_lds(
      (const __attribute__((address_space(1))) void*)g,
      (__attribute__((address_space(3))) void*)l, 16, 0, 0);
}

// ---------------------------------------------------------------------------
// Fused fp32->bf16 convert of x + 4 weights into contiguous bf16 workspace.
// ---------------------------------------------------------------------------
__global__ __launch_bounds__(256)
void cvt_all(const float* __restrict__ x, const float* __restrict__ wq,
             const float* __restrict__ wk, const float* __restrict__ wv,
             const float* __restrict__ wo, __bf16* __restrict__ out) {
  size_t idx = ((size_t)blockIdx.x * 256 + threadIdx.x) * 8;
  const float* src;
  if      (idx < XSZ)            src = x  + idx;
  else if (idx < XSZ + WSZ)      src = wq + (idx - XSZ);
  else if (idx < XSZ + 2 * WSZ)  src = wk + (idx - XSZ - WSZ);
  else if (idx < XSZ + 3 * WSZ)  src = wv + (idx - XSZ - 2 * WSZ);
  else                           src = wo + (idx - XSZ - 3 * WSZ);
  float4 a = *reinterpret_cast<const float4*>(src);
  float4 b = *reinterpret_cast<const float4*>(src + 4);
  bf16x8 o;
  o[0] = (__bf16)a.x; o[1] = (__bf16)a.y; o[2] = (__bf16)a.z; o[3] = (__bf16)a.w;
  o[4] = (__bf16)b.x; o[5] = (__bf16)b.y; o[6] = (__bf16)b.z; o[7] = (__bf16)b.w;
  *reinterpret_cast<bf16x8*>(out + idx) = o;
}

// ---------------------------------------------------------------------------
// MFMA GEMM, m97-style global_load_lds staging. C[m,n] = sum_k A[m,k]*W[n,k].
// 128x128 tile, BK=64, 512 threads = 8 waves (4x2), per-wave 32x64.
// MODE 1: fused QKV. grid.x in [0,24): which = x>>3 picks wq/wk/wv.
//   Q,K: RoPE fused in epilogue -> [bh][t][hd].  V: transposed -> [bh][hd][t].
// MODE 0: single GEMM (wo), fp32 out [M][1024].
// ---------------------------------------------------------------------------
template<int MODE>
__global__ __launch_bounds__(512)
void gemm_mfma(const __bf16* __restrict__ A,
               const __bf16* __restrict__ W0, const __bf16* __restrict__ W1,
               const __bf16* __restrict__ W2,
               const float* __restrict__ cosT, const float* __restrict__ sinT,
               void* __restrict__ out0, void* __restrict__ out1,
               void* __restrict__ out2) {
  __shared__ __bf16 As[128 * 64];
  __shared__ __bf16 Bs[128 * 64];

  const int tid  = threadIdx.x;
  const int lane = tid & 63;
  const int w    = tid >> 6;     // 0..7
  const int wm   = w >> 1;       // 0..3 (32 rows each)
  const int wn   = w & 1;        // 0..1 (64 cols each)
  const int l15  = lane & 15, lg = lane >> 4;
  const int m0   = blockIdx.y * 128;

  int which, n0;
  const __bf16* Bw;
  if (MODE == 1) {
    which = blockIdx.x >> 3;
    n0 = (blockIdx.x & 7) * 128;
    Bw = which == 0 ? W0 : which == 1 ? W1 : W2;
  } else {
    which = 0;
    n0 = blockIdx.x * 128;
    Bw = W0;
  }

  f32x4 acc[2][4];
  #pragma unroll
  for (int i = 0; i < 2; ++i)
    #pragma unroll
    for (int j = 0; j < 4; ++j) acc[i][j] = (f32x4){0.f, 0.f, 0.f, 0.f};

  const int e0 = tid * 8;        // 0..4095
  const int r0 = e0 >> 6;        // 0..63
  const int c0 = e0 & 63;

  for (int k0 = 0; k0 < 1024; k0 += 64) {
    const __bf16* ga = A  + (size_t)(m0 + r0) * 1024 + k0 + c0;
    const __bf16* gb = Bw + (size_t)(n0 + r0) * 1024 + k0 + c0;
    gload16(ga,             As + e0);
    gload16(ga + 64 * 1024, As + e0 + 4096);
    gload16(gb,             Bs + e0);
    gload16(gb + 64 * 1024, Bs + e0 + 4096);
    __syncthreads();   // drains vmcnt -> LDS tiles ready

    #pragma unroll
    for (int ks = 0; ks < 2; ++ks) {
      bf16x8 af[2], bfr[4];
      #pragma unroll
      for (int mt = 0; mt < 2; ++mt)
        af[mt] = *reinterpret_cast<const bf16x8*>(
            &As[(wm * 32 + mt * 16 + l15) * 64 + ks * 32 + lg * 8]);
      #pragma unroll
      for (int nt = 0; nt < 4; ++nt)
        bfr[nt] = *reinterpret_cast<const bf16x8*>(
            &Bs[(wn * 64 + nt * 16 + l15) * 64 + ks * 32 + lg * 8]);
      #pragma unroll
      for (int mt = 0; mt < 2; ++mt)
        #pragma unroll
        for (int nt = 0; nt < 4; ++nt)
          acc[mt][nt] = mfma16(af[mt], bfr[nt], acc[mt][nt]);
    }
    __syncthreads();
  }

  // Epilogue. Frag: n = n0 + wn*64 + nt*16 + l15 ; m = m0 + wm*32 + mt*16 + lg*4 + r
  if (MODE == 0) {
    float* o = (float*)out0;
    #pragma unroll
    for (int mt = 0; mt < 2; ++mt) {
      const int mb = m0 + wm * 32 + mt * 16 + lg * 4;
      #pragma unroll
      for (int nt = 0; nt < 4; ++nt) {
        const int n = n0 + wn * 64 + nt * 16 + l15;
        #pragma unroll
        for (int r = 0; r < 4; ++r)
          o[(size_t)(mb + r) * 1024 + n] = acc[mt][nt][r];
      }
    }
  } else if (which < 2) {
    // Q or K: RoPE fused. Pair (hd, hd+32) = (nt, nt+2) within this wave.
    __bf16* dst = which == 0 ? (__bf16*)out0 : (__bf16*)out1;
    const int h = (n0 + wn * 64) >> 6;
    #pragma unroll
    for (int mt = 0; mt < 2; ++mt) {
      const int tb   = m0 + wm * 32 + mt * 16 + lg * 4;
      const int bb   = tb >> 11;
      const int tloc = tb & 2047;
      #pragma unroll
      for (int r = 0; r < 4; ++r) {
        const int t = tloc + r;
        #pragma unroll
        for (int nt = 0; nt < 2; ++nt) {
          const int hd = nt * 16 + l15;
          const float c = cosT[t * HD + hd];
          const float s = sinT[t * HD + hd];
          const float v1 = acc[mt][nt][r];
          const float v2 = acc[mt][nt + 2][r];
          const size_t base = (((size_t)(bb * H + h)) * T + t) * HD;
          dst[base + hd]      = (__bf16)(v1 * c - v2 * s);
          dst[base + hd + 32] = (__bf16)(v2 * c + v1 * s);
        }
      }
    }
  } else {
    // V: transposed store [bh][hd][t], t contiguous over r -> bf16x4
    __bf16* dst = (__bf16*)out2;
    const int h = (n0 + wn * 64) >> 6;
    #pragma unroll
    for (int mt = 0; mt < 2; ++mt) {
      const int tb = m0 + wm * 32 + mt * 16 + lg * 4;
      const int bb = tb >> 11;
      const int t0 = tb & 2047;
      #pragma unroll
      for (int nt = 0; nt < 4; ++nt) {
        const int hd = nt * 16 + l15;
        bf16x4 ov;
        #pragma unroll
        for (int r = 0; r < 4; ++r) ov[r] = (__bf16)acc[mt][nt][r];
        *reinterpret_cast<bf16x4*>(
            &dst[(((size_t)(bb * H + h)) * HD + hd) * T + t0]) = ov;
      }
    }
  }
}

// ---------------------------------------------------------------------------
// attn_v4: occupancy-oriented flash attention.
// Block = 256 thr (4 waves), one 64-row q-block (16 rows/wave).
// Grid (32, 32) = 1024 blocks; LPT order (longest q-blocks dispatched first).
// LDS ~41KB -> 3 blocks/CU resident = 12 waves/CU with decorrelated phases.
// K/V tiles double-buffered via global_load_lds, counted vmcnt, XOR swizzle.
// Softmax in exp2 domain. Q,K: [bh][t][64] rope'd. Vt: [bh][64][t].
// Out: bf16 [M][1024].
// ---------------------------------------------------------------------------
__global__ __launch_bounds__(256)
void attn_v4(const __bf16* __restrict__ Q, const __bf16* __restrict__ K,
             const __bf16* __restrict__ Vt, __bf16* __restrict__ Ob) {
  __shared__ __bf16 Kl[2][64 * 64];   // 16 KB
  __shared__ __bf16 Vl[2][64 * 64];   // 16 KB
  __shared__ __bf16 Ps[4][16][68];    // 8.5 KB

  const int tid  = threadIdx.x;
  const int lane = tid & 63;
  const int w    = tid >> 6;
  const int l15  = lane & 15, lg = lane >> 4;
  const int qb   = 31 - (int)blockIdx.x;   // LPT: long jobs first
  const int bh   = blockIdx.y;
  const int qbase = qb * 64;
  const int q0    = qbase + w * 16;        // this wave's first q row

  const __bf16* Qg = Q  + (size_t)bh * T * HD;
  const __bf16* Kg = K  + (size_t)bh * T * HD;
  const __bf16* Vg = Vt + (size_t)bh * HD * T;

  // Staging geometry: tile = 64 rows x 8 chunks of 16B; 512 chunks / 256 thr.
  // LDS linear chunk li holds global chunk (li&7) ^ (row&7) of row li>>3.
  const int r0a = tid >> 3;          // 0..31
  const int r0b = r0a + 32;
  const int c0  = tid & 7;
  const int cda = c0 ^ (r0a & 7);
  const int cdb = cda;               // (r0b & 7) == (r0a & 7)

  // Q fragments (2 halves of head dim)
  bf16x8 qf0 = *reinterpret_cast<const bf16x8*>(Qg + (size_t)(q0 + l15) * HD + lg * 8);
  bf16x8 qf1 = *reinterpret_cast<const bf16x8*>(Qg + (size_t)(q0 + l15) * HD + 32 + lg * 8);

  float m_run = -INFINITY, l_run = 0.f;
  f32x4 oacc[4];
  #pragma unroll
  for (int i = 0; i < 4; ++i) oacc[i] = (f32x4){0.f, 0.f, 0.f, 0.f};

  const int nkb = qb + 1;

#define STAGE(kb_, buf_)                                                      \
  do {                                                                        \
    const int _j0 = (kb_) * 64;                                               \
    gload16(Kg + (size_t)(_j0 + r0a) * HD + cda * 8, &Kl[buf_][tid * 8]);     \
    gload16(Kg + (size_t)(_j0 + r0b) * HD + cdb * 8, &Kl[buf_][(tid + 256) * 8]); \
    gload16(Vg + (size_t)r0a * T + _j0 + cda * 8,    &Vl[buf_][tid * 8]);     \
    gload16(Vg + (size_t)r0b * T + _j0 + cdb * 8,    &Vl[buf_][(tid + 256) * 8]); \
  } while (0)

  STAGE(0, 0);

  const float SCALE = 0.125f * 1.44269504f;   // fold log2(e): exp2 domain

  #pragma unroll 1
  for (int kb = 0; kb < nkb; ++kb) {
    const int cur = kb & 1;
    if (kb + 1 < nkb) {
      STAGE(kb + 1, cur ^ 1);
      asm volatile("s_waitcnt vmcnt(4)" ::: "memory");
    } else {
      asm volatile("s_waitcnt vmcnt(0)" ::: "memory");
    }
    __builtin_amdgcn_s_barrier();
    __builtin_amdgcn_sched_barrier(0);

    const int j0 = kb * 64;
    // ---- QK^T (swapped): rows=key, cols=q ----
    f32x4 sa[4];
    #pragma unroll
    for (int kt = 0; kt < 4; ++kt) sa[kt] = (f32x4){0.f, 0.f, 0.f, 0.f};
    #pragma unroll
    for (int ks = 0; ks < 2; ++ks) {
      bf16x8 kf[4];
      #pragma unroll
      for (int kt = 0; kt < 4; ++kt) {
        const int row = kt * 16 + l15;
        const int c   = ks * 4 + lg;
        kf[kt] = *reinterpret_cast<const bf16x8*>(
            &Kl[cur][row * 64 + ((c ^ (row & 7)) << 3)]);
      }
      #pragma unroll
      for (int kt = 0; kt < 4; ++kt)
        sa[kt] = mfma16(kf[kt], ks ? qf1 : qf0, sa[kt]);
    }

    // ---- online softmax (exp2 domain); lane: q = l15, keys kt*16+lg*4+r ----
    float p[16];
    float smax = -INFINITY;
    if (j0 + 63 > q0) {          // diagonal tile: apply causal mask
      #pragma unroll
      for (int kt = 0; kt < 4; ++kt)
        #pragma unroll
        for (int r = 0; r < 4; ++r) {
          float s = sa[kt][r] * SCALE;
          if ((j0 + kt * 16 + lg * 4 + r) > q0 + l15) s = -INFINITY;
          p[kt * 4 + r] = s;
          smax = fmaxf(smax, s);
        }
    } else {
      #pragma unroll
      for (int kt = 0; kt < 4; ++kt)
        #pragma unroll
        for (int r = 0; r < 4; ++r) {
          float s = sa[kt][r] * SCALE;
          p[kt * 4 + r] = s;
          smax = fmaxf(smax, s);
        }
    }
    smax = fmaxf(smax, __shfl_xor(smax, 16));
    smax = fmaxf(smax, __shfl_xor(smax, 32));
    const float m_new = fmaxf(m_run, smax);
    const float resc  = exp2f(m_run - m_new);
    float psum = 0.f;
    #pragma unroll
    for (int i = 0; i < 16; ++i) {
      float e = exp2f(p[i] - m_new);
      p[i] = e;
      psum += e;
    }
    psum += __shfl_xor(psum, 16);
    psum += __shfl_xor(psum, 32);
    l_run = l_run * resc + psum;
    m_run = m_new;
    #pragma unroll
    for (int dt = 0; dt < 4; ++dt) oacc[dt] *= resc;

    // publish P^T rows (q = l15) to per-wave LDS
    #pragma unroll
    for (int kt = 0; kt < 4; ++kt) {
      bf16x4 pk;
      #pragma unroll
      for (int r = 0; r < 4; ++r) pk[r] = (__bf16)p[kt * 4 + r];
      *reinterpret_cast<bf16x4*>(&Ps[w][l15][kt * 16 + lg * 4]) = pk;
    }

    // ---- PV: O^T += V^T . P^T ----
    __builtin_amdgcn_s_setprio(1);
    #pragma unroll
    for (int ks = 0; ks < 2; ++ks) {
      bf16x8 pf = *reinterpret_cast<const bf16x8*>(
          &Ps[w][l15][ks * 32 + lg * 8]);
      #pragma unroll
      for (int dt = 0; dt < 4; ++dt) {
        const int row = dt * 16 + l15;
        const int c   = ks * 4 + lg;
        bf16x8 vf = *reinterpret_cast<const bf16x8*>(
            &Vl[cur][row * 64 + ((c ^ (row & 7)) << 3)]);
        oacc[dt] = mfma16(vf, pf, oacc[dt]);
      }
    }
    __builtin_amdgcn_s_setprio(0);

    __builtin_amdgcn_sched_barrier(0);
    __builtin_amdgcn_s_barrier();
  }
#undef STAGE

  // ---- epilogue: O rows hd = dt*16+lg*4+r, q col = l15 ----
  const float inv = 1.f / l_run;
  const int b = bh >> 4, h = bh & 15;
  const int q_abs = q0 + l15;
  const size_t rowbase = ((size_t)(b * T + q_abs)) * 1024 + h * 64;
  #pragma unroll
  for (int dt = 0; dt < 4; ++dt) {
    bf16x4 o;
    #pragma unroll
    for (int r = 0; r < 4; ++r) o[r] = (__bf16)(oacc[dt][r] * inv);
    *reinterpret_cast<bf16x4*>(&Ob[rowbase + dt * 16 + lg * 4]) = o;
  }
}

// ---------------------------------------------------------------------------
extern "C" void kernel_launch(void* const* d_in, const int* in_sizes, int n_in,
                              void* d_out, int out_size, void* d_ws, size_t ws_size,
                              hipStream_t stream) {
  const float* x    = (const float*)d_in[0];
  const float* cosT = (const float*)d_in[1];
  const float* sinT = (const float*)d_in[2];
  // d_in[3] = mask (causal, analytic)
  const float* wq   = (const float*)d_in[4];
  const float* wk   = (const float*)d_in[5];
  const float* wv   = (const float*)d_in[6];
  const float* wo   = (const float*)d_in[7];
  float* out = (float*)d_out;

  __bf16* xb   = (__bf16*)d_ws;
  __bf16* wqb  = xb  + XSZ;
  __bf16* wkb  = wqb + WSZ;
  __bf16* wvb  = wkb + WSZ;
  __bf16* wob  = wvb + WSZ;
  __bf16* Qh   = wob + WSZ;      // [bh][t][hd]
  __bf16* Kh   = Qh  + XSZ;      // [bh][t][hd]
  __bf16* Vth  = Kh  + XSZ;      // [bh][hd][t]
  __bf16* attb = Vth + XSZ;      // [M][1024]

  cvt_all<<<(XSZ + 4 * WSZ) / 8 / 256, 256, 0, stream>>>(x, wq, wk, wv, wo, xb);

  gemm_mfma<1><<<dim3(24, 32), 512, 0, stream>>>(
      xb, wqb, wkb, wvb, cosT, sinT, Qh, Kh, Vth);

  attn_v4<<<dim3(32, 32), 256, 0, stream>>>(Qh, Kh, Vth, attb);

  gemm_mfma<0><<<dim3(8, 32), 512, 0, stream>>>(
      attb, wob, nullptr, nullptr, nullptr, nullptr, out, nullptr, nullptr);
}

// Round 6
// 177.568 us; speedup vs baseline: 1.0156x; 1.0156x over previous
//
#include <hip/hip_runtime.h>
#include <math.h>

constexpr int D  = 1024;
constexpr int H  = 16;
constexpr int HD = 64;
constexpr int B  = 2;
constexpr int T  = 2048;
constexpr int M  = B * T;   // 4096

constexpr size_t XSZ = (size_t)M * D;   // 4,194,304
constexpr size_t WSZ = (size_t)D * D;   // 1,048,576

typedef float  f32x4  __attribute__((ext_vector_type(4)));
typedef __bf16 bf16x8 __attribute__((ext_vector_type(8)));
typedef __bf16 bf16x4 __attribute__((ext_vector_type(4)));

static __device__ inline f32x4 mfma16(bf16x8 a, bf16x8 b, f32x4 c) {
  return __builtin_amdgcn_mfma_f32_16x16x32_bf16(a, b, c, 0, 0, 0);
}

// async global->LDS, 16B per lane (dest = wave-uniform base + lane*16)
static __device__ inline void gload16(const __bf16* g, __bf16* l) {
  __builtin_amdgcn_global_load_lds(
      (const __attribute__((address_space(1))) void*)g,
      (__attribute__((address_space(3))) void*)l, 16, 0, 0);
}

// ---------------------------------------------------------------------------
// Fused fp32->bf16 convert of x + 4 weights into contiguous bf16 workspace.
// ---------------------------------------------------------------------------
__global__ __launch_bounds__(256)
void cvt_all(const float* __restrict__ x, const float* __restrict__ wq,
             const float* __restrict__ wk, const float* __restrict__ wv,
             const float* __restrict__ wo, __bf16* __restrict__ out) {
  size_t idx = ((size_t)blockIdx.x * 256 + threadIdx.x) * 8;
  const float* src;
  if      (idx < XSZ)            src = x  + idx;
  else if (idx < XSZ + WSZ)      src = wq + (idx - XSZ);
  else if (idx < XSZ + 2 * WSZ)  src = wk + (idx - XSZ - WSZ);
  else if (idx < XSZ + 3 * WSZ)  src = wv + (idx - XSZ - 2 * WSZ);
  else                           src = wo + (idx - XSZ - 3 * WSZ);
  float4 a = *reinterpret_cast<const float4*>(src);
  float4 b = *reinterpret_cast<const float4*>(src + 4);
  bf16x8 o;
  o[0] = (__bf16)a.x; o[1] = (__bf16)a.y; o[2] = (__bf16)a.z; o[3] = (__bf16)a.w;
  o[4] = (__bf16)b.x; o[5] = (__bf16)b.y; o[6] = (__bf16)b.z; o[7] = (__bf16)b.w;
  *reinterpret_cast<bf16x8*>(out + idx) = o;
}

// ---------------------------------------------------------------------------
// MFMA GEMM, m97-style global_load_lds staging. C[m,n] = sum_k A[m,k]*W[n,k].
// 128x128 tile, BK=64, 512 threads = 8 waves (4x2), per-wave 32x64.
// MODE 1: fused QKV. grid.x in [0,24): which = x>>3 picks wq/wk/wv.
//   Q,K: RoPE fused in epilogue -> [bh][t][hd].  V: transposed -> [bh][hd][t].
// MODE 0: single GEMM (wo), fp32 out [M][1024].
// ---------------------------------------------------------------------------
template<int MODE>
__global__ __launch_bounds__(512)
void gemm_mfma(const __bf16* __restrict__ A,
               const __bf16* __restrict__ W0, const __bf16* __restrict__ W1,
               const __bf16* __restrict__ W2,
               const float* __restrict__ cosT, const float* __restrict__ sinT,
               void* __restrict__ out0, void* __restrict__ out1,
               void* __restrict__ out2) {
  __shared__ __bf16 As[128 * 64];
  __shared__ __bf16 Bs[128 * 64];

  const int tid  = threadIdx.x;
  const int lane = tid & 63;
  const int w    = tid >> 6;     // 0..7
  const int wm   = w >> 1;       // 0..3 (32 rows each)
  const int wn   = w & 1;        // 0..1 (64 cols each)
  const int l15  = lane & 15, lg = lane >> 4;
  const int m0   = blockIdx.y * 128;

  int which, n0;
  const __bf16* Bw;
  if (MODE == 1) {
    which = blockIdx.x >> 3;
    n0 = (blockIdx.x & 7) * 128;
    Bw = which == 0 ? W0 : which == 1 ? W1 : W2;
  } else {
    which = 0;
    n0 = blockIdx.x * 128;
    Bw = W0;
  }

  f32x4 acc[2][4];
  #pragma unroll
  for (int i = 0; i < 2; ++i)
    #pragma unroll
    for (int j = 0; j < 4; ++j) acc[i][j] = (f32x4){0.f, 0.f, 0.f, 0.f};

  const int e0 = tid * 8;        // 0..4095
  const int r0 = e0 >> 6;        // 0..63
  const int c0 = e0 & 63;

  for (int k0 = 0; k0 < 1024; k0 += 64) {
    const __bf16* ga = A  + (size_t)(m0 + r0) * 1024 + k0 + c0;
    const __bf16* gb = Bw + (size_t)(n0 + r0) * 1024 + k0 + c0;
    gload16(ga,             As + e0);
    gload16(ga + 64 * 1024, As + e0 + 4096);
    gload16(gb,             Bs + e0);
    gload16(gb + 64 * 1024, Bs + e0 + 4096);
    __syncthreads();   // drains vmcnt -> LDS tiles ready

    #pragma unroll
    for (int ks = 0; ks < 2; ++ks) {
      bf16x8 af[2], bfr[4];
      #pragma unroll
      for (int mt = 0; mt < 2; ++mt)
        af[mt] = *reinterpret_cast<const bf16x8*>(
            &As[(wm * 32 + mt * 16 + l15) * 64 + ks * 32 + lg * 8]);
      #pragma unroll
      for (int nt = 0; nt < 4; ++nt)
        bfr[nt] = *reinterpret_cast<const bf16x8*>(
            &Bs[(wn * 64 + nt * 16 + l15) * 64 + ks * 32 + lg * 8]);
      #pragma unroll
      for (int mt = 0; mt < 2; ++mt)
        #pragma unroll
        for (int nt = 0; nt < 4; ++nt)
          acc[mt][nt] = mfma16(af[mt], bfr[nt], acc[mt][nt]);
    }
    __syncthreads();
  }

  // Epilogue. Frag: n = n0 + wn*64 + nt*16 + l15 ; m = m0 + wm*32 + mt*16 + lg*4 + r
  if (MODE == 0) {
    float* o = (float*)out0;
    #pragma unroll
    for (int mt = 0; mt < 2; ++mt) {
      const int mb = m0 + wm * 32 + mt * 16 + lg * 4;
      #pragma unroll
      for (int nt = 0; nt < 4; ++nt) {
        const int n = n0 + wn * 64 + nt * 16 + l15;
        #pragma unroll
        for (int r = 0; r < 4; ++r)
          o[(size_t)(mb + r) * 1024 + n] = acc[mt][nt][r];
      }
    }
  } else if (which < 2) {
    // Q or K: RoPE fused. Pair (hd, hd+32) = (nt, nt+2) within this wave.
    __bf16* dst = which == 0 ? (__bf16*)out0 : (__bf16*)out1;
    const int h = (n0 + wn * 64) >> 6;
    #pragma unroll
    for (int mt = 0; mt < 2; ++mt) {
      const int tb   = m0 + wm * 32 + mt * 16 + lg * 4;
      const int bb   = tb >> 11;
      const int tloc = tb & 2047;
      #pragma unroll
      for (int r = 0; r < 4; ++r) {
        const int t = tloc + r;
        #pragma unroll
        for (int nt = 0; nt < 2; ++nt) {
          const int hd = nt * 16 + l15;
          const float c = cosT[t * HD + hd];
          const float s = sinT[t * HD + hd];
          const float v1 = acc[mt][nt][r];
          const float v2 = acc[mt][nt + 2][r];
          const size_t base = (((size_t)(bb * H + h)) * T + t) * HD;
          dst[base + hd]      = (__bf16)(v1 * c - v2 * s);
          dst[base + hd + 32] = (__bf16)(v2 * c + v1 * s);
        }
      }
    }
  } else {
    // V: transposed store [bh][hd][t], t contiguous over r -> bf16x4
    __bf16* dst = (__bf16*)out2;
    const int h = (n0 + wn * 64) >> 6;
    #pragma unroll
    for (int mt = 0; mt < 2; ++mt) {
      const int tb = m0 + wm * 32 + mt * 16 + lg * 4;
      const int bb = tb >> 11;
      const int t0 = tb & 2047;
      #pragma unroll
      for (int nt = 0; nt < 4; ++nt) {
        const int hd = nt * 16 + l15;
        bf16x4 ov;
        #pragma unroll
        for (int r = 0; r < 4; ++r) ov[r] = (__bf16)acc[mt][nt][r];
        *reinterpret_cast<bf16x4*>(
            &dst[(((size_t)(bb * H + h)) * HD + hd) * T + t0]) = ov;
      }
    }
  }
}

// ---------------------------------------------------------------------------
// attn_v5: v3 geometry (128-row q-block, 32 rows/wave, 34 tiles max) +
// v4's conflict-free XOR swizzle + exp2 softmax, UNPAIRED so grid = (16,32)
// = 512 blocks = 2/CU resident (LDS 49.4KB -> 3 fit). LPT: qb = 15-x.
// K/V double-buffered via global_load_lds, counted vmcnt.
// Q,K: [bh][t][64] rope'd. Vt: [bh][64][t]. Out: bf16 [M][1024].
// ---------------------------------------------------------------------------
__global__ __launch_bounds__(256)
void attn_v5(const __bf16* __restrict__ Q, const __bf16* __restrict__ K,
             const __bf16* __restrict__ Vt, __bf16* __restrict__ Ob) {
  __shared__ __bf16 Kl[2][64 * 64];   // 16 KB
  __shared__ __bf16 Vl[2][64 * 64];   // 16 KB
  __shared__ __bf16 Ps[4][32][68];    // 17 KB

  const int tid  = threadIdx.x;
  const int lane = tid & 63;
  const int w    = tid >> 6;
  const int l15  = lane & 15, lg = lane >> 4;
  const int qb   = 15 - (int)blockIdx.x;   // LPT: long q-blocks first
  const int bh   = blockIdx.y;
  const int qbase = qb * 128;
  const int q0    = qbase + w * 32;        // wave's 32 q-rows

  const __bf16* Qg = Q  + (size_t)bh * T * HD;
  const __bf16* Kg = K  + (size_t)bh * T * HD;
  const __bf16* Vg = Vt + (size_t)bh * HD * T;

  // Staging: tile = 64 rows x 8 chunks of 16B; LDS linear chunk li holds
  // global chunk (li&7) ^ (row&7) of row li>>3  (inverse-swizzled source).
  const int r0a = tid >> 3;          // 0..31
  const int r0b = r0a + 32;
  const int c0  = tid & 7;
  const int cda = c0 ^ (r0a & 7);    // == c0 ^ (r0b & 7)

#define STAGE(kb_, buf_)                                                      \
  do {                                                                        \
    const int _j0 = (kb_) * 64;                                               \
    gload16(Kg + (size_t)(_j0 + r0a) * HD + cda * 8, &Kl[buf_][tid * 8]);     \
    gload16(Kg + (size_t)(_j0 + r0b) * HD + cda * 8, &Kl[buf_][(tid + 256) * 8]); \
    gload16(Vg + (size_t)r0a * T + _j0 + cda * 8,    &Vl[buf_][tid * 8]);     \
    gload16(Vg + (size_t)r0b * T + _j0 + cda * 8,    &Vl[buf_][(tid + 256) * 8]); \
  } while (0)

  // Q fragments: 2 q-groups x 2 halves
  bf16x8 qf[2][2];
  #pragma unroll
  for (int qg = 0; qg < 2; ++qg) {
    const int qa = q0 + qg * 16 + l15;
    qf[qg][0] = *reinterpret_cast<const bf16x8*>(Qg + (size_t)qa * HD + lg * 8);
    qf[qg][1] = *reinterpret_cast<const bf16x8*>(Qg + (size_t)qa * HD + 32 + lg * 8);
  }

  float m_run[2] = {-INFINITY, -INFINITY};
  float l_run[2] = {0.f, 0.f};
  f32x4 oacc[2][4];
  #pragma unroll
  for (int qg = 0; qg < 2; ++qg)
    #pragma unroll
    for (int dt = 0; dt < 4; ++dt) oacc[qg][dt] = (f32x4){0.f, 0.f, 0.f, 0.f};

  const int nkb = 2 * qb + 2;
  STAGE(0, 0);

  const float SCALE = 0.125f * 1.44269504f;   // exp2 domain

  #pragma unroll 1
  for (int kb = 0; kb < nkb; ++kb) {
    const int cur = kb & 1;
    if (kb + 1 < nkb) {
      STAGE(kb + 1, cur ^ 1);
      asm volatile("s_waitcnt vmcnt(4)" ::: "memory");
    } else {
      asm volatile("s_waitcnt vmcnt(0)" ::: "memory");
    }
    __builtin_amdgcn_s_barrier();
    __builtin_amdgcn_sched_barrier(0);

    const int j0 = kb * 64;
    // ---- QK^T (swapped): sa[qg][kt], rows=key, cols=q ----
    f32x4 sa[2][4];
    #pragma unroll
    for (int qg = 0; qg < 2; ++qg)
      #pragma unroll
      for (int kt = 0; kt < 4; ++kt) sa[qg][kt] = (f32x4){0.f, 0.f, 0.f, 0.f};
    #pragma unroll
    for (int ks = 0; ks < 2; ++ks) {
      bf16x8 kf[4];
      #pragma unroll
      for (int kt = 0; kt < 4; ++kt) {
        const int row = kt * 16 + l15;
        const int c   = ks * 4 + lg;
        kf[kt] = *reinterpret_cast<const bf16x8*>(
            &Kl[cur][row * 64 + ((c ^ (row & 7)) << 3)]);
      }
      #pragma unroll
      for (int qg = 0; qg < 2; ++qg)
        #pragma unroll
        for (int kt = 0; kt < 4; ++kt)
          sa[qg][kt] = mfma16(kf[kt], qf[qg][ks], sa[qg][kt]);
    }

    // ---- online softmax per q-group (exp2); lane: q=l15, keys kt*16+lg*4+r
    #pragma unroll
    for (int qg = 0; qg < 2; ++qg) {
      const int q_abs = q0 + qg * 16 + l15;
      const bool diag = (j0 + 63 > q0 + qg * 16);
      float p[16];
      float smax = -INFINITY;
      #pragma unroll
      for (int kt = 0; kt < 4; ++kt)
        #pragma unroll
        for (int r = 0; r < 4; ++r) {
          float s = sa[qg][kt][r] * SCALE;
          if (diag && (j0 + kt * 16 + lg * 4 + r) > q_abs) s = -INFINITY;
          p[kt * 4 + r] = s;
          smax = fmaxf(smax, s);
        }
      smax = fmaxf(smax, __shfl_xor(smax, 16));
      smax = fmaxf(smax, __shfl_xor(smax, 32));
      const float m_new = fmaxf(m_run[qg], smax);
      const float resc  = exp2f(m_run[qg] - m_new);
      float psum = 0.f;
      #pragma unroll
      for (int i = 0; i < 16; ++i) {
        float e = exp2f(p[i] - m_new);
        p[i] = e;
        psum += e;
      }
      psum += __shfl_xor(psum, 16);
      psum += __shfl_xor(psum, 32);
      l_run[qg] = l_run[qg] * resc + psum;
      m_run[qg] = m_new;
      #pragma unroll
      for (int dt = 0; dt < 4; ++dt) oacc[qg][dt] *= resc;

      // publish P^T rows (q = qg*16+l15) to per-wave LDS
      #pragma unroll
      for (int kt = 0; kt < 4; ++kt) {
        bf16x4 pk;
        #pragma unroll
        for (int r = 0; r < 4; ++r) pk[r] = (__bf16)p[kt * 4 + r];
        *reinterpret_cast<bf16x4*>(&Ps[w][qg * 16 + l15][kt * 16 + lg * 4]) = pk;
      }
    }

    // ---- PV: O^T += V^T . P^T ----
    __builtin_amdgcn_s_setprio(1);
    #pragma unroll
    for (int ks = 0; ks < 2; ++ks) {
      bf16x8 pf[2];
      #pragma unroll
      for (int qg = 0; qg < 2; ++qg)
        pf[qg] = *reinterpret_cast<const bf16x8*>(
            &Ps[w][qg * 16 + l15][ks * 32 + lg * 8]);
      #pragma unroll
      for (int dt = 0; dt < 4; ++dt) {
        const int row = dt * 16 + l15;
        const int c   = ks * 4 + lg;
        bf16x8 vf = *reinterpret_cast<const bf16x8*>(
            &Vl[cur][row * 64 + ((c ^ (row & 7)) << 3)]);
        #pragma unroll
        for (int qg = 0; qg < 2; ++qg)
          oacc[qg][dt] = mfma16(vf, pf[qg], oacc[qg][dt]);
      }
    }
    __builtin_amdgcn_s_setprio(0);

    __builtin_amdgcn_sched_barrier(0);
    __builtin_amdgcn_s_barrier();
  }
#undef STAGE

  // ---- epilogue: O rows hd = dt*16+lg*4+r, q col = l15 ----
  const int b = bh >> 4, h = bh & 15;
  #pragma unroll
  for (int qg = 0; qg < 2; ++qg) {
    const int q_abs = q0 + qg * 16 + l15;
    const float inv = 1.f / l_run[qg];
    const size_t rowbase = ((size_t)(b * T + q_abs)) * 1024 + h * 64;
    #pragma unroll
    for (int dt = 0; dt < 4; ++dt) {
      bf16x4 o;
      #pragma unroll
      for (int r = 0; r < 4; ++r) o[r] = (__bf16)(oacc[qg][dt][r] * inv);
      *reinterpret_cast<bf16x4*>(&Ob[rowbase + dt * 16 + lg * 4]) = o;
    }
  }
}

// ---------------------------------------------------------------------------
extern "C" void kernel_launch(void* const* d_in, const int* in_sizes, int n_in,
                              void* d_out, int out_size, void* d_ws, size_t ws_size,
                              hipStream_t stream) {
  const float* x    = (const float*)d_in[0];
  const float* cosT = (const float*)d_in[1];
  const float* sinT = (const float*)d_in[2];
  // d_in[3] = mask (causal, analytic)
  const float* wq   = (const float*)d_in[4];
  const float* wk   = (const float*)d_in[5];
  const float* wv   = (const float*)d_in[6];
  const float* wo   = (const float*)d_in[7];
  float* out = (float*)d_out;

  __bf16* xb   = (__bf16*)d_ws;
  __bf16* wqb  = xb  + XSZ;
  __bf16* wkb  = wqb + WSZ;
  __bf16* wvb  = wkb + WSZ;
  __bf16* wob  = wvb + WSZ;
  __bf16* Qh   = wob + WSZ;      // [bh][t][hd]
  __bf16* Kh   = Qh  + XSZ;      // [bh][t][hd]
  __bf16* Vth  = Kh  + XSZ;      // [bh][hd][t]
  __bf16* attb = Vth + XSZ;      // [M][1024]

  cvt_all<<<(XSZ + 4 * WSZ) / 8 / 256, 256, 0, stream>>>(x, wq, wk, wv, wo, xb);

  gemm_mfma<1><<<dim3(24, 32), 512, 0, stream>>>(
      xb, wqb, wkb, wvb, cosT, sinT, Qh, Kh, Vth);

  attn_v5<<<dim3(16, 32), 256, 0, stream>>>(Qh, Kh, Vth, attb);

  gemm_mfma<0><<<dim3(8, 32), 512, 0, stream>>>(
      attb, wob, nullptr, nullptr, nullptr, nullptr, out, nullptr, nullptr);
}

// Round 7
// 159.639 us; speedup vs baseline: 1.1297x; 1.1123x over previous
//
#include <hip/hip_runtime.h>
#include <math.h>

constexpr int D  = 1024;
constexpr int H  = 16;
constexpr int HD = 64;
constexpr int B  = 2;
constexpr int T  = 2048;
constexpr int M  = B * T;   // 4096

constexpr size_t XSZ = (size_t)M * D;   // 4,194,304
constexpr size_t WSZ = (size_t)D * D;   // 1,048,576

typedef float  f32x4  __attribute__((ext_vector_type(4)));
typedef __bf16 bf16x8 __attribute__((ext_vector_type(8)));
typedef __bf16 bf16x4 __attribute__((ext_vector_type(4)));

static __device__ inline f32x4 mfma16(bf16x8 a, bf16x8 b, f32x4 c) {
  return __builtin_amdgcn_mfma_f32_16x16x32_bf16(a, b, c, 0, 0, 0);
}

// async global->LDS, 16B per lane (dest = wave-uniform base + lane*16)
static __device__ inline void gload16(const __bf16* g, __bf16* l) {
  __builtin_amdgcn_global_load_lds(
      (const __attribute__((address_space(1))) void*)g,
      (__attribute__((address_space(3))) void*)l, 16, 0, 0);
}

// ---------------------------------------------------------------------------
// Fused fp32->bf16 convert of x + 4 weights into contiguous bf16 workspace.
// ---------------------------------------------------------------------------
__global__ __launch_bounds__(256)
void cvt_all(const float* __restrict__ x, const float* __restrict__ wq,
             const float* __restrict__ wk, const float* __restrict__ wv,
             const float* __restrict__ wo, __bf16* __restrict__ out) {
  size_t idx = ((size_t)blockIdx.x * 256 + threadIdx.x) * 8;
  const float* src;
  if      (idx < XSZ)            src = x  + idx;
  else if (idx < XSZ + WSZ)      src = wq + (idx - XSZ);
  else if (idx < XSZ + 2 * WSZ)  src = wk + (idx - XSZ - WSZ);
  else if (idx < XSZ + 3 * WSZ)  src = wv + (idx - XSZ - 2 * WSZ);
  else                           src = wo + (idx - XSZ - 3 * WSZ);
  float4 a = *reinterpret_cast<const float4*>(src);
  float4 b = *reinterpret_cast<const float4*>(src + 4);
  bf16x8 o;
  o[0] = (__bf16)a.x; o[1] = (__bf16)a.y; o[2] = (__bf16)a.z; o[3] = (__bf16)a.w;
  o[4] = (__bf16)b.x; o[5] = (__bf16)b.y; o[6] = (__bf16)b.z; o[7] = (__bf16)b.w;
  *reinterpret_cast<bf16x8*>(out + idx) = o;
}

// ---------------------------------------------------------------------------
// MFMA GEMM, m97-style global_load_lds staging. C[m,n] = sum_k A[m,k]*W[n,k].
// 128x128 tile, BK=64, 512 threads = 8 waves (4x2), per-wave 32x64.
// MODE 1: fused QKV. grid.x in [0,24): which = x>>3 picks wq/wk/wv.
//   Q,K: RoPE fused in epilogue -> [bh][t][hd].  V: transposed -> [bh][hd][t].
// MODE 0: single GEMM (wo), fp32 out [M][1024].
// ---------------------------------------------------------------------------
template<int MODE>
__global__ __launch_bounds__(512)
void gemm_mfma(const __bf16* __restrict__ A,
               const __bf16* __restrict__ W0, const __bf16* __restrict__ W1,
               const __bf16* __restrict__ W2,
               const float* __restrict__ cosT, const float* __restrict__ sinT,
               void* __restrict__ out0, void* __restrict__ out1,
               void* __restrict__ out2) {
  __shared__ __bf16 As[128 * 64];
  __shared__ __bf16 Bs[128 * 64];

  const int tid  = threadIdx.x;
  const int lane = tid & 63;
  const int w    = tid >> 6;     // 0..7
  const int wm   = w >> 1;       // 0..3 (32 rows each)
  const int wn   = w & 1;        // 0..1 (64 cols each)
  const int l15  = lane & 15, lg = lane >> 4;
  const int m0   = blockIdx.y * 128;

  int which, n0;
  const __bf16* Bw;
  if (MODE == 1) {
    which = blockIdx.x >> 3;
    n0 = (blockIdx.x & 7) * 128;
    Bw = which == 0 ? W0 : which == 1 ? W1 : W2;
  } else {
    which = 0;
    n0 = blockIdx.x * 128;
    Bw = W0;
  }

  f32x4 acc[2][4];
  #pragma unroll
  for (int i = 0; i < 2; ++i)
    #pragma unroll
    for (int j = 0; j < 4; ++j) acc[i][j] = (f32x4){0.f, 0.f, 0.f, 0.f};

  const int e0 = tid * 8;        // 0..4095
  const int r0 = e0 >> 6;        // 0..63
  const int c0 = e0 & 63;

  for (int k0 = 0; k0 < 1024; k0 += 64) {
    const __bf16* ga = A  + (size_t)(m0 + r0) * 1024 + k0 + c0;
    const __bf16* gb = Bw + (size_t)(n0 + r0) * 1024 + k0 + c0;
    gload16(ga,             As + e0);
    gload16(ga + 64 * 1024, As + e0 + 4096);
    gload16(gb,             Bs + e0);
    gload16(gb + 64 * 1024, Bs + e0 + 4096);
    __syncthreads();   // drains vmcnt -> LDS tiles ready

    #pragma unroll
    for (int ks = 0; ks < 2; ++ks) {
      bf16x8 af[2], bfr[4];
      #pragma unroll
      for (int mt = 0; mt < 2; ++mt)
        af[mt] = *reinterpret_cast<const bf16x8*>(
            &As[(wm * 32 + mt * 16 + l15) * 64 + ks * 32 + lg * 8]);
      #pragma unroll
      for (int nt = 0; nt < 4; ++nt)
        bfr[nt] = *reinterpret_cast<const bf16x8*>(
            &Bs[(wn * 64 + nt * 16 + l15) * 64 + ks * 32 + lg * 8]);
      #pragma unroll
      for (int mt = 0; mt < 2; ++mt)
        #pragma unroll
        for (int nt = 0; nt < 4; ++nt)
          acc[mt][nt] = mfma16(af[mt], bfr[nt], acc[mt][nt]);
    }
    __syncthreads();
  }

  // Epilogue. Frag: n = n0 + wn*64 + nt*16 + l15 ; m = m0 + wm*32 + mt*16 + lg*4 + r
  if (MODE == 0) {
    float* o = (float*)out0;
    #pragma unroll
    for (int mt = 0; mt < 2; ++mt) {
      const int mb = m0 + wm * 32 + mt * 16 + lg * 4;
      #pragma unroll
      for (int nt = 0; nt < 4; ++nt) {
        const int n = n0 + wn * 64 + nt * 16 + l15;
        #pragma unroll
        for (int r = 0; r < 4; ++r)
          o[(size_t)(mb + r) * 1024 + n] = acc[mt][nt][r];
      }
    }
  } else if (which < 2) {
    // Q or K: RoPE fused. Pair (hd, hd+32) = (nt, nt+2) within this wave.
    __bf16* dst = which == 0 ? (__bf16*)out0 : (__bf16*)out1;
    const int h = (n0 + wn * 64) >> 6;
    #pragma unroll
    for (int mt = 0; mt < 2; ++mt) {
      const int tb   = m0 + wm * 32 + mt * 16 + lg * 4;
      const int bb   = tb >> 11;
      const int tloc = tb & 2047;
      #pragma unroll
      for (int r = 0; r < 4; ++r) {
        const int t = tloc + r;
        #pragma unroll
        for (int nt = 0; nt < 2; ++nt) {
          const int hd = nt * 16 + l15;
          const float c = cosT[t * HD + hd];
          const float s = sinT[t * HD + hd];
          const float v1 = acc[mt][nt][r];
          const float v2 = acc[mt][nt + 2][r];
          const size_t base = (((size_t)(bb * H + h)) * T + t) * HD;
          dst[base + hd]      = (__bf16)(v1 * c - v2 * s);
          dst[base + hd + 32] = (__bf16)(v2 * c + v1 * s);
        }
      }
    }
  } else {
    // V: transposed store [bh][hd][t], t contiguous over r -> bf16x4
    __bf16* dst = (__bf16*)out2;
    const int h = (n0 + wn * 64) >> 6;
    #pragma unroll
    for (int mt = 0; mt < 2; ++mt) {
      const int tb = m0 + wm * 32 + mt * 16 + lg * 4;
      const int bb = tb >> 11;
      const int t0 = tb & 2047;
      #pragma unroll
      for (int nt = 0; nt < 4; ++nt) {
        const int hd = nt * 16 + l15;
        bf16x4 ov;
        #pragma unroll
        for (int r = 0; r < 4; ++r) ov[r] = (__bf16)acc[mt][nt][r];
        *reinterpret_cast<bf16x4*>(
            &dst[(((size_t)(bb * H + h)) * HD + hd) * T + t0]) = ov;
      }
    }
  }
}

// ---------------------------------------------------------------------------
// attn_v6: v5 + CU-pairing-aware balance.
// Dispatch arithmetic on MI355X (8 XCD x 32 CU round-robin): linear blocks
// i and i+256 land on the SAME CU. i+256 has the same blockIdx.x (y+16),
// so qb must flip with the y-half to give co-resident blocks complementary
// lengths: qb = (bh<16) ? 15-x : x  ->  every CU does exactly 34 kv-tiles.
// Everything else identical to v5 (conflict-free swizzle, exp2 softmax,
// double-buffered global_load_lds, counted vmcnt).
// ---------------------------------------------------------------------------
__global__ __launch_bounds__(256)
void attn_v6(const __bf16* __restrict__ Q, const __bf16* __restrict__ K,
             const __bf16* __restrict__ Vt, __bf16* __restrict__ Ob) {
  __shared__ __bf16 Kl[2][64 * 64];   // 16 KB
  __shared__ __bf16 Vl[2][64 * 64];   // 16 KB
  __shared__ __bf16 Ps[4][32][68];    // 17 KB

  const int tid  = threadIdx.x;
  const int lane = tid & 63;
  const int w    = tid >> 6;
  const int l15  = lane & 15, lg = lane >> 4;
  const int bh   = blockIdx.y;
  // complementary-length pairing across the two y-halves (see header)
  const int qb   = (bh < 16) ? (15 - (int)blockIdx.x) : (int)blockIdx.x;
  const int qbase = qb * 128;
  const int q0    = qbase + w * 32;        // wave's 32 q-rows

  const __bf16* Qg = Q  + (size_t)bh * T * HD;
  const __bf16* Kg = K  + (size_t)bh * T * HD;
  const __bf16* Vg = Vt + (size_t)bh * HD * T;

  // Staging: tile = 64 rows x 8 chunks of 16B; LDS linear chunk li holds
  // global chunk (li&7) ^ (row&7) of row li>>3  (inverse-swizzled source).
  const int r0a = tid >> 3;          // 0..31
  const int r0b = r0a + 32;
  const int c0  = tid & 7;
  const int cda = c0 ^ (r0a & 7);    // == c0 ^ (r0b & 7)

#define STAGE(kb_, buf_)                                                      \
  do {                                                                        \
    const int _j0 = (kb_) * 64;                                               \
    gload16(Kg + (size_t)(_j0 + r0a) * HD + cda * 8, &Kl[buf_][tid * 8]);     \
    gload16(Kg + (size_t)(_j0 + r0b) * HD + cda * 8, &Kl[buf_][(tid + 256) * 8]); \
    gload16(Vg + (size_t)r0a * T + _j0 + cda * 8,    &Vl[buf_][tid * 8]);     \
    gload16(Vg + (size_t)r0b * T + _j0 + cda * 8,    &Vl[buf_][(tid + 256) * 8]); \
  } while (0)

  // Q fragments: 2 q-groups x 2 halves
  bf16x8 qf[2][2];
  #pragma unroll
  for (int qg = 0; qg < 2; ++qg) {
    const int qa = q0 + qg * 16 + l15;
    qf[qg][0] = *reinterpret_cast<const bf16x8*>(Qg + (size_t)qa * HD + lg * 8);
    qf[qg][1] = *reinterpret_cast<const bf16x8*>(Qg + (size_t)qa * HD + 32 + lg * 8);
  }

  float m_run[2] = {-INFINITY, -INFINITY};
  float l_run[2] = {0.f, 0.f};
  f32x4 oacc[2][4];
  #pragma unroll
  for (int qg = 0; qg < 2; ++qg)
    #pragma unroll
    for (int dt = 0; dt < 4; ++dt) oacc[qg][dt] = (f32x4){0.f, 0.f, 0.f, 0.f};

  const int nkb = 2 * qb + 2;
  STAGE(0, 0);

  const float SCALE = 0.125f * 1.44269504f;   // exp2 domain

  #pragma unroll 1
  for (int kb = 0; kb < nkb; ++kb) {
    const int cur = kb & 1;
    if (kb + 1 < nkb) {
      STAGE(kb + 1, cur ^ 1);
      asm volatile("s_waitcnt vmcnt(4)" ::: "memory");
    } else {
      asm volatile("s_waitcnt vmcnt(0)" ::: "memory");
    }
    __builtin_amdgcn_s_barrier();
    __builtin_amdgcn_sched_barrier(0);

    const int j0 = kb * 64;
    // ---- QK^T (swapped): sa[qg][kt], rows=key, cols=q ----
    f32x4 sa[2][4];
    #pragma unroll
    for (int qg = 0; qg < 2; ++qg)
      #pragma unroll
      for (int kt = 0; kt < 4; ++kt) sa[qg][kt] = (f32x4){0.f, 0.f, 0.f, 0.f};
    #pragma unroll
    for (int ks = 0; ks < 2; ++ks) {
      bf16x8 kf[4];
      #pragma unroll
      for (int kt = 0; kt < 4; ++kt) {
        const int row = kt * 16 + l15;
        const int c   = ks * 4 + lg;
        kf[kt] = *reinterpret_cast<const bf16x8*>(
            &Kl[cur][row * 64 + ((c ^ (row & 7)) << 3)]);
      }
      #pragma unroll
      for (int qg = 0; qg < 2; ++qg)
        #pragma unroll
        for (int kt = 0; kt < 4; ++kt)
          sa[qg][kt] = mfma16(kf[kt], qf[qg][ks], sa[qg][kt]);
    }

    // ---- online softmax per q-group (exp2); lane: q=l15, keys kt*16+lg*4+r
    #pragma unroll
    for (int qg = 0; qg < 2; ++qg) {
      const int q_abs = q0 + qg * 16 + l15;
      const bool diag = (j0 + 63 > q0 + qg * 16);
      float p[16];
      float smax = -INFINITY;
      #pragma unroll
      for (int kt = 0; kt < 4; ++kt)
        #pragma unroll
        for (int r = 0; r < 4; ++r) {
          float s = sa[qg][kt][r] * SCALE;
          if (diag && (j0 + kt * 16 + lg * 4 + r) > q_abs) s = -INFINITY;
          p[kt * 4 + r] = s;
          smax = fmaxf(smax, s);
        }
      smax = fmaxf(smax, __shfl_xor(smax, 16));
      smax = fmaxf(smax, __shfl_xor(smax, 32));
      const float m_new = fmaxf(m_run[qg], smax);
      const float resc  = exp2f(m_run[qg] - m_new);
      float psum = 0.f;
      #pragma unroll
      for (int i = 0; i < 16; ++i) {
        float e = exp2f(p[i] - m_new);
        p[i] = e;
        psum += e;
      }
      psum += __shfl_xor(psum, 16);
      psum += __shfl_xor(psum, 32);
      l_run[qg] = l_run[qg] * resc + psum;
      m_run[qg] = m_new;
      #pragma unroll
      for (int dt = 0; dt < 4; ++dt) oacc[qg][dt] *= resc;

      // publish P^T rows (q = qg*16+l15) to per-wave LDS
      #pragma unroll
      for (int kt = 0; kt < 4; ++kt) {
        bf16x4 pk;
        #pragma unroll
        for (int r = 0; r < 4; ++r) pk[r] = (__bf16)p[kt * 4 + r];
        *reinterpret_cast<bf16x4*>(&Ps[w][qg * 16 + l15][kt * 16 + lg * 4]) = pk;
      }
    }

    // ---- PV: O^T += V^T . P^T ----
    __builtin_amdgcn_s_setprio(1);
    #pragma unroll
    for (int ks = 0; ks < 2; ++ks) {
      bf16x8 pf[2];
      #pragma unroll
      for (int qg = 0; qg < 2; ++qg)
        pf[qg] = *reinterpret_cast<const bf16x8*>(
            &Ps[w][qg * 16 + l15][ks * 32 + lg * 8]);
      #pragma unroll
      for (int dt = 0; dt < 4; ++dt) {
        const int row = dt * 16 + l15;
        const int c   = ks * 4 + lg;
        bf16x8 vf = *reinterpret_cast<const bf16x8*>(
            &Vl[cur][row * 64 + ((c ^ (row & 7)) << 3)]);
        #pragma unroll
        for (int qg = 0; qg < 2; ++qg)
          oacc[qg][dt] = mfma16(vf, pf[qg], oacc[qg][dt]);
      }
    }
    __builtin_amdgcn_s_setprio(0);

    __builtin_amdgcn_sched_barrier(0);
    __builtin_amdgcn_s_barrier();
  }
#undef STAGE

  // ---- epilogue: O rows hd = dt*16+lg*4+r, q col = l15 ----
  const int b = bh >> 4, h = bh & 15;
  #pragma unroll
  for (int qg = 0; qg < 2; ++qg) {
    const int q_abs = q0 + qg * 16 + l15;
    const float inv = 1.f / l_run[qg];
    const size_t rowbase = ((size_t)(b * T + q_abs)) * 1024 + h * 64;
    #pragma unroll
    for (int dt = 0; dt < 4; ++dt) {
      bf16x4 o;
      #pragma unroll
      for (int r = 0; r < 4; ++r) o[r] = (__bf16)(oacc[qg][dt][r] * inv);
      *reinterpret_cast<bf16x4*>(&Ob[rowbase + dt * 16 + lg * 4]) = o;
    }
  }
}

// ---------------------------------------------------------------------------
extern "C" void kernel_launch(void* const* d_in, const int* in_sizes, int n_in,
                              void* d_out, int out_size, void* d_ws, size_t ws_size,
                              hipStream_t stream) {
  const float* x    = (const float*)d_in[0];
  const float* cosT = (const float*)d_in[1];
  const float* sinT = (const float*)d_in[2];
  // d_in[3] = mask (causal, analytic)
  const float* wq   = (const float*)d_in[4];
  const float* wk   = (const float*)d_in[5];
  const float* wv   = (const float*)d_in[6];
  const float* wo   = (const float*)d_in[7];
  float* out = (float*)d_out;

  __bf16* xb   = (__bf16*)d_ws;
  __bf16* wqb  = xb  + XSZ;
  __bf16* wkb  = wqb + WSZ;
  __bf16* wvb  = wkb + WSZ;
  __bf16* wob  = wvb + WSZ;
  __bf16* Qh   = wob + WSZ;      // [bh][t][hd]
  __bf16* Kh   = Qh  + XSZ;      // [bh][t][hd]
  __bf16* Vth  = Kh  + XSZ;      // [bh][hd][t]
  __bf16* attb = Vth + XSZ;      // [M][1024]

  cvt_all<<<(XSZ + 4 * WSZ) / 8 / 256, 256, 0, stream>>>(x, wq, wk, wv, wo, xb);

  gemm_mfma<1><<<dim3(24, 32), 512, 0, stream>>>(
      xb, wqb, wkb, wvb, cosT, sinT, Qh, Kh, Vth);

  attn_v6<<<dim3(16, 32), 256, 0, stream>>>(Qh, Kh, Vth, attb);

  gemm_mfma<0><<<dim3(8, 32), 512, 0, stream>>>(
      attb, wob, nullptr, nullptr, nullptr, nullptr, out, nullptr, nullptr);
}

// Round 9
// 154.048 us; speedup vs baseline: 1.1707x; 1.0363x over previous
//
#include <hip/hip_runtime.h>
#include <math.h>

constexpr int D  = 1024;
constexpr int H  = 16;
constexpr int HD = 64;
constexpr int B  = 2;
constexpr int T  = 2048;
constexpr int M  = B * T;   // 4096

constexpr size_t XSZ = (size_t)M * D;   // 4,194,304
constexpr size_t WSZ = (size_t)D * D;   // 1,048,576

typedef float  f32x4   __attribute__((ext_vector_type(4)));
typedef float  f32x16  __attribute__((ext_vector_type(16)));
typedef __bf16 bf16x8  __attribute__((ext_vector_type(8)));
typedef __bf16 bf16x4  __attribute__((ext_vector_type(4)));
typedef unsigned u32x2 __attribute__((ext_vector_type(2)));
typedef unsigned u32x4 __attribute__((ext_vector_type(4)));

static __device__ inline f32x4 mfma16(bf16x8 a, bf16x8 b, f32x4 c) {
  return __builtin_amdgcn_mfma_f32_16x16x32_bf16(a, b, c, 0, 0, 0);
}
static __device__ inline f32x16 mfma32(bf16x8 a, bf16x8 b, f32x16 c) {
  return __builtin_amdgcn_mfma_f32_32x32x16_bf16(a, b, c, 0, 0, 0);
}
// pack two f32 -> u32 of 2 bf16 (lo = a, hi = b); no builtin on gfx950
static __device__ inline unsigned cvtpk(float a, float b) {
  unsigned r;
  asm("v_cvt_pk_bf16_f32 %0, %1, %2" : "=v"(r) : "v"(a), "v"(b));
  return r;
}
static __device__ inline u32x2 plswap(unsigned a, unsigned b) {
  return __builtin_amdgcn_permlane32_swap(a, b, false, false);
}
// async global->LDS, 16B per lane (dest = wave-uniform base + lane*16)
static __device__ inline void gload16(const __bf16* g, __bf16* l) {
  __builtin_amdgcn_global_load_lds(
      (const __attribute__((address_space(1))) void*)g,
      (__attribute__((address_space(3))) void*)l, 16, 0, 0);
}

// ---------------------------------------------------------------------------
// Fused fp32->bf16 convert of x + 4 weights into contiguous bf16 workspace.
// ---------------------------------------------------------------------------
__global__ __launch_bounds__(256)
void cvt_all(const float* __restrict__ x, const float* __restrict__ wq,
             const float* __restrict__ wk, const float* __restrict__ wv,
             const float* __restrict__ wo, __bf16* __restrict__ out) {
  size_t idx = ((size_t)blockIdx.x * 256 + threadIdx.x) * 8;
  const float* src;
  if      (idx < XSZ)            src = x  + idx;
  else if (idx < XSZ + WSZ)      src = wq + (idx - XSZ);
  else if (idx < XSZ + 2 * WSZ)  src = wk + (idx - XSZ - WSZ);
  else if (idx < XSZ + 3 * WSZ)  src = wv + (idx - XSZ - 2 * WSZ);
  else                           src = wo + (idx - XSZ - 3 * WSZ);
  float4 a = *reinterpret_cast<const float4*>(src);
  float4 b = *reinterpret_cast<const float4*>(src + 4);
  bf16x8 o;
  o[0] = (__bf16)a.x; o[1] = (__bf16)a.y; o[2] = (__bf16)a.z; o[3] = (__bf16)a.w;
  o[4] = (__bf16)b.x; o[5] = (__bf16)b.y; o[6] = (__bf16)b.z; o[7] = (__bf16)b.w;
  *reinterpret_cast<bf16x8*>(out + idx) = o;
}

// ---------------------------------------------------------------------------
// MFMA GEMM, global_load_lds staging. C[m,n] = sum_k A[m,k]*W[n,k].
// MODE 1: fused QKV; Q gets softmax-scale (0.125*log2e) folded into RoPE.
// MODE 0: single GEMM (wo), fp32 out.
// ---------------------------------------------------------------------------
template<int MODE>
__global__ __launch_bounds__(512)
void gemm_mfma(const __bf16* __restrict__ A,
               const __bf16* __restrict__ W0, const __bf16* __restrict__ W1,
               const __bf16* __restrict__ W2,
               const float* __restrict__ cosT, const float* __restrict__ sinT,
               void* __restrict__ out0, void* __restrict__ out1,
               void* __restrict__ out2) {
  __shared__ __bf16 As[128 * 64];
  __shared__ __bf16 Bs[128 * 64];

  const int tid  = threadIdx.x;
  const int lane = tid & 63;
  const int w    = tid >> 6;     // 0..7
  const int wm   = w >> 1;       // 0..3 (32 rows each)
  const int wn   = w & 1;        // 0..1 (64 cols each)
  const int l15  = lane & 15, lg = lane >> 4;
  const int m0   = blockIdx.y * 128;

  int which, n0;
  const __bf16* Bw;
  if (MODE == 1) {
    which = blockIdx.x >> 3;
    n0 = (blockIdx.x & 7) * 128;
    Bw = which == 0 ? W0 : which == 1 ? W1 : W2;
  } else {
    which = 0;
    n0 = blockIdx.x * 128;
    Bw = W0;
  }

  f32x4 acc[2][4];
  #pragma unroll
  for (int i = 0; i < 2; ++i)
    #pragma unroll
    for (int j = 0; j < 4; ++j) acc[i][j] = (f32x4){0.f, 0.f, 0.f, 0.f};

  const int e0 = tid * 8;        // 0..4095
  const int r0 = e0 >> 6;        // 0..63
  const int c0 = e0 & 63;

  for (int k0 = 0; k0 < 1024; k0 += 64) {
    const __bf16* ga = A  + (size_t)(m0 + r0) * 1024 + k0 + c0;
    const __bf16* gb = Bw + (size_t)(n0 + r0) * 1024 + k0 + c0;
    gload16(ga,             As + e0);
    gload16(ga + 64 * 1024, As + e0 + 4096);
    gload16(gb,             Bs + e0);
    gload16(gb + 64 * 1024, Bs + e0 + 4096);
    __syncthreads();

    #pragma unroll
    for (int ks = 0; ks < 2; ++ks) {
      bf16x8 af[2], bfr[4];
      #pragma unroll
      for (int mt = 0; mt < 2; ++mt)
        af[mt] = *reinterpret_cast<const bf16x8*>(
            &As[(wm * 32 + mt * 16 + l15) * 64 + ks * 32 + lg * 8]);
      #pragma unroll
      for (int nt = 0; nt < 4; ++nt)
        bfr[nt] = *reinterpret_cast<const bf16x8*>(
            &Bs[(wn * 64 + nt * 16 + l15) * 64 + ks * 32 + lg * 8]);
      #pragma unroll
      for (int mt = 0; mt < 2; ++mt)
        #pragma unroll
        for (int nt = 0; nt < 4; ++nt)
          acc[mt][nt] = mfma16(af[mt], bfr[nt], acc[mt][nt]);
    }
    __syncthreads();
  }

  if (MODE == 0) {
    float* o = (float*)out0;
    #pragma unroll
    for (int mt = 0; mt < 2; ++mt) {
      const int mb = m0 + wm * 32 + mt * 16 + lg * 4;
      #pragma unroll
      for (int nt = 0; nt < 4; ++nt) {
        const int n = n0 + wn * 64 + nt * 16 + l15;
        #pragma unroll
        for (int r = 0; r < 4; ++r)
          o[(size_t)(mb + r) * 1024 + n] = acc[mt][nt][r];
      }
    }
  } else if (which < 2) {
    // Q or K: RoPE fused; Q additionally scaled by 0.125*log2(e).
    __bf16* dst = which == 0 ? (__bf16*)out0 : (__bf16*)out1;
    const float qs = (which == 0) ? 0.180336880f : 1.0f;
    const int h = (n0 + wn * 64) >> 6;
    #pragma unroll
    for (int mt = 0; mt < 2; ++mt) {
      const int tb   = m0 + wm * 32 + mt * 16 + lg * 4;
      const int bb   = tb >> 11;
      const int tloc = tb & 2047;
      #pragma unroll
      for (int r = 0; r < 4; ++r) {
        const int t = tloc + r;
        #pragma unroll
        for (int nt = 0; nt < 2; ++nt) {
          const int hd = nt * 16 + l15;
          const float c = cosT[t * HD + hd];
          const float s = sinT[t * HD + hd];
          const float v1 = acc[mt][nt][r];
          const float v2 = acc[mt][nt + 2][r];
          const size_t base = (((size_t)(bb * H + h)) * T + t) * HD;
          dst[base + hd]      = (__bf16)((v1 * c - v2 * s) * qs);
          dst[base + hd + 32] = (__bf16)((v2 * c + v1 * s) * qs);
        }
      }
    }
  } else {
    // V: transposed store [bh][hd][t]
    __bf16* dst = (__bf16*)out2;
    const int h = (n0 + wn * 64) >> 6;
    #pragma unroll
    for (int mt = 0; mt < 2; ++mt) {
      const int tb = m0 + wm * 32 + mt * 16 + lg * 4;
      const int bb = tb >> 11;
      const int t0 = tb & 2047;
      #pragma unroll
      for (int nt = 0; nt < 4; ++nt) {
        const int hd = nt * 16 + l15;
        bf16x4 ov;
        #pragma unroll
        for (int r = 0; r < 4; ++r) ov[r] = (__bf16)acc[mt][nt][r];
        *reinterpret_cast<bf16x4*>(
            &dst[(((size_t)(bb * H + h)) * HD + hd) * T + t0]) = ov;
      }
    }
  }
}

// ---------------------------------------------------------------------------
// attn_v7b: 32x32 MFMA + in-register softmax. Identical to v7 except the
// causal-mask gate: mask iff the tile's last key exceeds the wave's FIRST q
// (j0+63 > q0w), not the last q. v7's (q0w+31) left wave 1's diagonal tile
// unmasked -> future-key leakage (absmax 0.22).
// ---------------------------------------------------------------------------
__global__ __launch_bounds__(128)
void attn_v7b(const __bf16* __restrict__ Q, const __bf16* __restrict__ K,
              const __bf16* __restrict__ Vt, __bf16* __restrict__ Ob) {
  __shared__ __bf16 Kl[2][64 * 64];   // 16 KB
  __shared__ __bf16 Vl[2][64 * 64];   // 16 KB

  const int tid  = threadIdx.x;
  const int lane = tid & 63;
  const int w    = tid >> 6;          // 0..1
  const int l31  = lane & 31;
  const int hi   = lane >> 5;         // 0..1
  const int x    = blockIdx.x;        // 0..31
  const int bh   = blockIdx.y;        // 0..31
  const int sel  = bh >> 3;           // co-resident blocks differ in sel
  const int qb   = sel == 0 ? x : sel == 1 ? (31 - x)
                 : sel == 2 ? ((x + 16) & 31) : ((15 - x) & 31);
  const int q0w  = qb * 64 + w * 32;  // wave's first q row
  const int nkb  = qb + 1;

  const __bf16* Qg = Q  + (size_t)bh * T * HD;
  const __bf16* Kg = K  + (size_t)bh * T * HD;
  const __bf16* Vg = Vt + (size_t)bh * HD * T;

  // Staging: 64 rows x 8 chunks of 16B = 512 chunks; 128 thr x 4 each.
  // LDS linear chunk (r*8+c) holds global chunk c^(r&7)  (involution).
  const int r0  = tid >> 3;           // 0..15
  const int c0  = tid & 7;
  const int csz = c0 ^ (r0 & 7);      // same for rows r0+16i

#define STAGE(kb_, buf_)                                                       \
  do {                                                                         \
    const int _j0 = (kb_) * 64;                                                \
    _Pragma("unroll")                                                          \
    for (int _i = 0; _i < 4; ++_i)                                             \
      gload16(Kg + (size_t)(_j0 + r0 + 16 * _i) * HD + csz * 8,                \
              &Kl[buf_][(tid + 128 * _i) * 8]);                                \
    _Pragma("unroll")                                                          \
    for (int _i = 0; _i < 4; ++_i)                                             \
      gload16(Vg + (size_t)(r0 + 16 * _i) * T + _j0 + csz * 8,                 \
              &Vl[buf_][(tid + 128 * _i) * 8]);                                \
  } while (0)

  // Q B-fragments: col=q=l31, k(step of 16 hd) -> hi*8 chunk
  bf16x8 qfr[4];
  #pragma unroll
  for (int st = 0; st < 4; ++st)
    qfr[st] = *reinterpret_cast<const bf16x8*>(
        Qg + (size_t)(q0w + l31) * HD + st * 16 + hi * 8);

  float m_run = -INFINITY, l_run = 0.f;
  f32x16 oacc[2];
  #pragma unroll
  for (int d2 = 0; d2 < 2; ++d2)
    #pragma unroll
    for (int i = 0; i < 16; ++i) oacc[d2][i] = 0.f;

  const int l7 = l31 & 7;
  STAGE(0, 0);

  #pragma unroll 1
  for (int kb = 0; kb < nkb; ++kb) {
    const int cur = kb & 1;
    if (kb + 1 < nkb) {
      STAGE(kb + 1, cur ^ 1);
      asm volatile("s_waitcnt vmcnt(8)" ::: "memory");
    } else {
      asm volatile("s_waitcnt vmcnt(0)" ::: "memory");
    }
    __builtin_amdgcn_s_barrier();
    __builtin_amdgcn_sched_barrier(0);

    const int j0 = kb * 64;

    // ---- QK^T: sv[s] = K[s-subtile] . Q  (rows=key, cols=q) ----
    f32x16 sv[2];
    #pragma unroll
    for (int s = 0; s < 2; ++s)
      #pragma unroll
      for (int i = 0; i < 16; ++i) sv[s][i] = 0.f;
    __builtin_amdgcn_s_setprio(1);
    #pragma unroll
    for (int st = 0; st < 4; ++st) {
      const int cc = st * 2 + hi;
      bf16x8 kf0 = *reinterpret_cast<const bf16x8*>(
          &Kl[cur][l31 * 64 + ((cc ^ l7) << 3)]);
      bf16x8 kf1 = *reinterpret_cast<const bf16x8*>(
          &Kl[cur][(32 + l31) * 64 + ((cc ^ l7) << 3)]);
      sv[0] = mfma32(kf0, qfr[st], sv[0]);
      sv[1] = mfma32(kf1, qfr[st], sv[1]);
    }
    __builtin_amdgcn_s_setprio(0);

    // ---- causal mask: needed iff tile's last key can exceed wave's min q ----
    if (j0 + 63 > q0w) {
      const int q = q0w + l31;
      #pragma unroll
      for (int reg = 0; reg < 16; ++reg) {
        const int key = j0 + (reg & 3) + 8 * (reg >> 2) + 4 * hi;
        if (key > q)      sv[0][reg] = -INFINITY;
        if (key + 32 > q) sv[1][reg] = -INFINITY;
      }
    }

    // ---- in-lane max tree + one cross-half exchange ----
    float mx[8];
    #pragma unroll
    for (int i = 0; i < 8; ++i)
      mx[i] = fmaxf(fmaxf(sv[0][i], sv[0][i + 8]),
                    fmaxf(sv[1][i], sv[1][i + 8]));
    #pragma unroll
    for (int stp = 4; stp > 0; stp >>= 1)
      #pragma unroll
      for (int i = 0; i < 4; ++i)
        if (i < stp) mx[i] = fmaxf(mx[i], mx[i + stp]);
    float pmax = fmaxf(mx[0], __shfl_xor(mx[0], 32));

    // ---- defer-max: only rescale when the running max grew by > 8 ----
    if (__any(pmax > m_run + 8.f)) {
      const float m_new = fmaxf(m_run, pmax);
      const float rs    = exp2f(m_run - m_new);
      l_run *= rs;
      #pragma unroll
      for (int d2 = 0; d2 < 2; ++d2)
        #pragma unroll
        for (int i = 0; i < 16; ++i) oacc[d2][i] *= rs;
      m_run = m_new;
    }

    // ---- exp2 + in-lane sum (cross-half summed once at epilogue) ----
    float sm[8];
    #pragma unroll
    for (int s = 0; s < 2; ++s)
      #pragma unroll
      for (int i = 0; i < 16; ++i) sv[s][i] = exp2f(sv[s][i] - m_run);
    #pragma unroll
    for (int i = 0; i < 8; ++i)
      sm[i] = (sv[0][i] + sv[0][i + 8]) + (sv[1][i] + sv[1][i + 8]);
    #pragma unroll
    for (int stp = 4; stp > 0; stp >>= 1)
      #pragma unroll
      for (int i = 0; i < 4; ++i)
        if (i < stp) sm[i] += sm[i + stp];
    l_run += sm[0];

    // ---- pack P to bf16 pairs: c[s][2m+j] = keys 8m+4hi+{2j,2j+1} ----
    unsigned cp[2][8];
    #pragma unroll
    for (int s = 0; s < 2; ++s)
      #pragma unroll
      for (int m = 0; m < 4; ++m) {
        cp[s][2 * m]     = cvtpk(sv[s][4 * m],     sv[s][4 * m + 1]);
        cp[s][2 * m + 1] = cvtpk(sv[s][4 * m + 2], sv[s][4 * m + 3]);
      }

    // ---- PV: O^T += V^T . P^T ; B-frags via permlane32_swap ----
    __builtin_amdgcn_s_setprio(1);
    #pragma unroll
    for (int s = 0; s < 2; ++s) {
      #pragma unroll
      for (int st = 0; st < 2; ++st) {
        u32x2 r0s = plswap(cp[s][4 * st],     cp[s][4 * st + 2]);
        u32x2 r1s = plswap(cp[s][4 * st + 1], cp[s][4 * st + 3]);
        union { u32x4 u; bf16x8 v; } pu;
        pu.u = (u32x4){r0s[0], r1s[0], r0s[1], r1s[1]};
        const int cc = s * 4 + st * 2 + hi;
        bf16x8 vf0 = *reinterpret_cast<const bf16x8*>(
            &Vl[cur][l31 * 64 + ((cc ^ l7) << 3)]);
        bf16x8 vf1 = *reinterpret_cast<const bf16x8*>(
            &Vl[cur][(32 + l31) * 64 + ((cc ^ l7) << 3)]);
        oacc[0] = mfma32(vf0, pu.v, oacc[0]);
        oacc[1] = mfma32(vf1, pu.v, oacc[1]);
      }
    }
    __builtin_amdgcn_s_setprio(0);

    __builtin_amdgcn_sched_barrier(0);
    __builtin_amdgcn_s_barrier();
  }
#undef STAGE

  // ---- epilogue: O[q][32d + 8rg + 4hi + r], q = l31 col ----
  const float l_tot = l_run + __shfl_xor(l_run, 32);
  const float inv = 1.f / l_tot;
  const int b = bh >> 4, h = bh & 15;
  const int q_abs = q0w + l31;
  const size_t rowbase = ((size_t)(b * T + q_abs)) * 1024 + h * 64;
  #pragma unroll
  for (int d2 = 0; d2 < 2; ++d2) {
    #pragma unroll
    for (int rg = 0; rg < 4; ++rg) {
      bf16x4 o;
      #pragma unroll
      for (int r = 0; r < 4; ++r) o[r] = (__bf16)(oacc[d2][rg * 4 + r] * inv);
      *reinterpret_cast<bf16x4*>(&Ob[rowbase + d2 * 32 + rg * 8 + hi * 4]) = o;
    }
  }
}

// ---------------------------------------------------------------------------
extern "C" void kernel_launch(void* const* d_in, const int* in_sizes, int n_in,
                              void* d_out, int out_size, void* d_ws, size_t ws_size,
                              hipStream_t stream) {
  const float* x    = (const float*)d_in[0];
  const float* cosT = (const float*)d_in[1];
  const float* sinT = (const float*)d_in[2];
  // d_in[3] = mask (causal, analytic)
  const float* wq   = (const float*)d_in[4];
  const float* wk   = (const float*)d_in[5];
  const float* wv   = (const float*)d_in[6];
  const float* wo   = (const float*)d_in[7];
  float* out = (float*)d_out;

  __bf16* xb   = (__bf16*)d_ws;
  __bf16* wqb  = xb  + XSZ;
  __bf16* wkb  = wqb + WSZ;
  __bf16* wvb  = wkb + WSZ;
  __bf16* wob  = wvb + WSZ;
  __bf16* Qh   = wob + WSZ;      // [bh][t][hd]  (pre-scaled by 0.125*log2e)
  __bf16* Kh   = Qh  + XSZ;      // [bh][t][hd]
  __bf16* Vth  = Kh  + XSZ;      // [bh][hd][t]
  __bf16* attb = Vth + XSZ;      // [M][1024]

  cvt_all<<<(XSZ + 4 * WSZ) / 8 / 256, 256, 0, stream>>>(x, wq, wk, wv, wo, xb);

  gemm_mfma<1><<<dim3(24, 32), 512, 0, stream>>>(
      xb, wqb, wkb, wvb, cosT, sinT, Qh, Kh, Vth);

  attn_v7b<<<dim3(32, 32), 128, 0, stream>>>(Qh, Kh, Vth, attb);

  gemm_mfma<0><<<dim3(8, 32), 512, 0, stream>>>(
      attb, wob, nullptr, nullptr, nullptr, nullptr, out, nullptr, nullptr);
}